// Round 13
// baseline (11154.295 us; speedup 1.0000x reference)
//
#include <hip/hip_runtime.h>
#include <type_traits>

// LSTM_69879117906487: T=256,B=256,I=1024,H=256,FC=128,C=8
// Round 13: 4-way j-split across 64 CUs. Analysis of R2..R12: all 16-block
// variants plateau 5.9-7.4 us/step because W (512KB) can't fit on one CU and
// 16 CUs carry all VALU. 4-way split: W-quarter (128KB) is FULLY LDS-resident
// (no stream, no pinning), VALU/CU quarters. Cross-block h-exchange with a
// minimal protocol (R3's failure was per-thread __threadfence + no overlap):
//   release: syncthreads(drains vmcnt) -> tid0: release-fence + prog store
//   acquire: tid0 relaxed-polls 3 partners -> acquire-fence -> syncthreads
//   partner h loaded FIRST, hidden under own-quarter MFMAs.
// prog[] is monotonic per-block (no reset races), zeroed each launch (k_init).

typedef float    f4    __attribute__((ext_vector_type(4)));
typedef float    f32x4 __attribute__((ext_vector_type(4)));
typedef _Float16 h8    __attribute__((ext_vector_type(8)));
typedef _Float16 h4    __attribute__((ext_vector_type(4)));

__device__ __forceinline__ float ldf(const float* p)    { return *p; }
__device__ __forceinline__ float ldf(const _Float16* p) { return (float)*p; }

__device__ __forceinline__ float fast_sigmoid(float x) {
    return 1.f / (1.f + __expf(-x));
}
__device__ __forceinline__ float fast_tanh(float x) {
    const float e = __expf(-2.f * fabsf(x));
    const float t = (1.f - e) / (1.f + e);
    return copysignf(t, x);
}

// ---------------------------------------------------------------- init sync
__global__ __launch_bounds__(64) void k_init(unsigned int* __restrict__ prog) {
    prog[threadIdx.x] = 0u;   // 64 block progress counters, every launch
}

// ---------------------------------------------------------------- W_hh pack
// fi = gt*8 + kb (gt = 16-gate-col tile 0..63). Lane l elem j:
// W_hh[gt*16 + (l&15)][kb*32 + (l>>4)*8 + j]; 16 B/lane.
__global__ __launch_bounds__(256) void k_pack(const float* __restrict__ W_hh,
                                              _Float16* __restrict__ Wp) {
    const int idx = blockIdx.x * 256 + threadIdx.x;
    const int fi = idx >> 6;
    const int l  = idx & 63;
    const int g  = (fi >> 3) * 16 + (l & 15);
    const int k  = (fi & 7) * 32 + ((l >> 4) << 3);
    const float* src = &W_hh[(size_t)g * 256 + k];
    h8 v;
    #pragma unroll
    for (int c = 0; c < 8; ++c) v[c] = (_Float16)src[c];
    *(h8*)&Wp[(size_t)idx * 8] = v;
}

// ---------------------------------------------------------------- xg GEMM (MFMA)
// 128x128 tile, BK=32, 256 thr. Bias folded in. Epilogue -> 32 B/lane packets
// for the 4-way-split consumer:
// base = (((((t*16+gb)*4 + s)*4 + w)*64 + lane)*16, elem = gate*4 + r,
// where gate = col>>8, s = (col>>6)&3, w = (col>>4)&3.
__global__ __launch_bounds__(256) void k_xg_mfma(
    const float* __restrict__ x, const float* __restrict__ W_ih,
    const float* __restrict__ b_ih, const float* __restrict__ b_hh,
    _Float16* __restrict__ xg2)
{
    __shared__ _Float16 As[2][128][40];
    __shared__ _Float16 Bs[2][128][40];
    const int tid = threadIdx.x;
    const int l   = tid & 63;
    const int w   = tid >> 6;
    const int m0  = blockIdx.y * 128;
    const int n0  = blockIdx.x * 128;
    const int wr  = (w >> 1) * 64;
    const int wc  = (w & 1) * 64;
    const int srow = tid >> 2;
    const int skof = (tid & 3) * 8;
    const int lr = l & 15;
    const int lg = l >> 4;

    f32x4 acc[4][4] = {};
    f4 ldA[2][2], ldB[2][2];

    auto XG_LOAD = [&](int kt) {
        const int k0 = kt * 32;
        #pragma unroll
        for (int s = 0; s < 2; ++s) {
            const float* xa = &x[(size_t)(m0 + srow + s * 64) * 1024 + k0 + skof];
            const float* wb = &W_ih[(size_t)(n0 + srow + s * 64) * 1024 + k0 + skof];
            ldA[s][0] = *(const f4*)xa; ldA[s][1] = *(const f4*)(xa + 4);
            ldB[s][0] = *(const f4*)wb; ldB[s][1] = *(const f4*)(wb + 4);
        }
    };
    auto XG_WRITE = [&](int buf) {
        #pragma unroll
        for (int s = 0; s < 2; ++s) {
            h8 va, vb;
            #pragma unroll
            for (int c = 0; c < 8; ++c) {
                va[c] = (_Float16)ldA[s][c >> 2][c & 3];
                vb[c] = (_Float16)ldB[s][c >> 2][c & 3];
            }
            *(h8*)&As[buf][srow + s * 64][skof] = va;
            *(h8*)&Bs[buf][srow + s * 64][skof] = vb;
        }
    };

    XG_LOAD(0);
    XG_WRITE(0);
    __syncthreads();
    for (int kt = 0; kt < 32; ++kt) {
        const int cur = kt & 1;
        if (kt + 1 < 32) XG_LOAD(kt + 1);
        h8 af[4], bf[4];
        #pragma unroll
        for (int mf = 0; mf < 4; ++mf) af[mf] = *(const h8*)&As[cur][wr + mf * 16 + lr][lg * 8];
        #pragma unroll
        for (int nf = 0; nf < 4; ++nf) bf[nf] = *(const h8*)&Bs[cur][wc + nf * 16 + lr][lg * 8];
        #pragma unroll
        for (int mf = 0; mf < 4; ++mf)
            #pragma unroll
            for (int nf = 0; nf < 4; ++nf)
                acc[mf][nf] = __builtin_amdgcn_mfma_f32_16x16x32_f16(af[mf], bf[nf], acc[mf][nf], 0, 0, 0);
        if (kt + 1 < 32) XG_WRITE((kt + 1) & 1);
        __syncthreads();
    }
    #pragma unroll
    for (int nf = 0; nf < 4; ++nf) {
        const int col  = n0 + wc + nf * 16 + lr;
        const float bv = b_ih[col] + b_hh[col];
        const int gate = col >> 8;
        const int sq   = (col >> 6) & 3;
        const int w4   = (col >> 4) & 3;
        #pragma unroll
        for (int mf = 0; mf < 4; ++mf) {
            const int rowb = m0 + wr + mf * 16 + lg * 4;
            const int tt = rowb >> 8;
            const int gb = (rowb >> 4) & 15;
            h4 pk;
            #pragma unroll
            for (int r = 0; r < 4; ++r) pk[r] = (_Float16)(acc[mf][nf][r] + bv);
            *(h4*)&xg2[(((((size_t)tt * 16 + gb) * 4 + sq) * 4 + w4) * 64 + l) * 16 + gate * 4] = pk;
        }
    }
}

// ---------------------------------------------------------------- recurrence
// 64 blocks = 16 batch-groups (g) x 4 j-quarters (s). bid = s*16 + g.
// Block: batch rows [16g,16g+16), j in [64s, 64s+64), all 4 gates.
// 256 thr (4 waves); wave w owns j-sub [64s+16w, +16): 4 gate-tiles x 8 kb.
// W-quarter: 128 frags, ALL in LDS. h exchange via h_all + prog[] protocol.
__global__ __launch_bounds__(256, 1) void k_lstm_4x(
    const _Float16* __restrict__ xg2, const _Float16* __restrict__ Wp,
    _Float16* __restrict__ h_all, unsigned int* __restrict__ prog)
{
    __shared__ _Float16 wlds[4 * 32 * 512];   // 131,072 B: [wave][gate*8+kb][lane*8]
    __shared__ _Float16 h_sh[2][16][72];      //   4,608 B  (own quarter, pad 72)
    const int tid = threadIdx.x;
    const int w   = tid >> 6;       // 0..3
    const int l   = tid & 63;
    const int lr  = l & 15;
    const int lg  = l >> 4;
    const int bid = blockIdx.x;
    const int s   = bid >> 4;
    const int g   = bid & 15;
    const int b0  = g * 16;

    // ---- prologue: load W-quarter into LDS (32 frags per thread's wave)
    #pragma unroll
    for (int ti = 0; ti < 4; ++ti) {
        #pragma unroll
        for (int kb = 0; kb < 8; ++kb) {
            const int gt = ti * 16 + s * 4 + w;
            const h8 v = *(const h8*)&Wp[((size_t)(gt * 8 + kb) * 64 + l) * 8];
            *(h8*)&wlds[((w * 32 + ti * 8 + kb) * 64 + l) * 8] = v;
        }
    }
    __syncthreads();

    float c[4] = {0.f, 0.f, 0.f, 0.f};

    // xg[0] packet (32 B/lane)
    h8 xq0, xq1;
    {
        const size_t E0 = ((((size_t)g * 4 + s) * 4 + w) * 64 + l) * 16;
        xq0 = *(const h8*)&xg2[E0];
        xq1 = *(const h8*)&xg2[E0 + 8];
    }

    for (int t = 0; t < 256; ++t) {
        const int cur = (t & 1) ^ 1;   // h[t-1] buffer
        const int nxt = t & 1;         // h[t] buffer

        // acc init = xg (includes biases)
        f32x4 acc[4];
        #pragma unroll
        for (int gate = 0; gate < 4; ++gate) {
            #pragma unroll
            for (int r = 0; r < 4; ++r) {
                const int v = gate * 4 + r;
                acc[gate][r] = (float)((v < 8) ? xq0[v] : xq1[v - 8]);
            }
        }

        // prefetch xg[t+1]
        h8 xqn0, xqn1;
        if (t < 255) {
            const size_t En = (((((size_t)(t + 1) * 16 + g) * 4 + s) * 4 + w) * 64 + l) * 16;
            xqn0 = *(const h8*)&xg2[En];
            xqn1 = *(const h8*)&xg2[En + 8];
        }

        if (t > 0) {
            // ---- acquire partners' h[t-1]
            if (tid == 0) {
                #pragma unroll
                for (int q = 0; q < 4; ++q) {
                    if (q == s) continue;
                    const unsigned int* pp = &prog[q * 16 + g];
                    while (__hip_atomic_load(pp, __ATOMIC_RELAXED,
                                             __HIP_MEMORY_SCOPE_AGENT) < (unsigned)t) { }
                }
                __builtin_amdgcn_fence(__ATOMIC_ACQUIRE, "agent");
            }
            __syncthreads();

            // issue partner A-frag loads FIRST (latency hides under own MFMAs)
            h8 ap[6];
            {
                int i = 0;
                const _Float16* hrow = &h_all[((size_t)(t - 1) * 256 + b0 + lr) * 256];
                #pragma unroll
                for (int q = 0; q < 4; ++q) {
                    if (q == s) continue;
                    #pragma unroll
                    for (int kk = 0; kk < 2; ++kk)
                        ap[i++] = *(const h8*)&hrow[(q * 2 + kk) * 32 + lg * 8];
                }
            }
            // own-quarter MFMAs (A from LDS)
            #pragma unroll
            for (int kk = 0; kk < 2; ++kk) {
                const h8 av = *(const h8*)&h_sh[cur][lr][kk * 32 + lg * 8];
                const int kb = s * 2 + kk;
                #pragma unroll
                for (int ti = 0; ti < 4; ++ti) {
                    const h8 b = *(const h8*)&wlds[((w * 32 + ti * 8 + kb) * 64 + l) * 8];
                    acc[ti] = __builtin_amdgcn_mfma_f32_16x16x32_f16(av, b, acc[ti], 0, 0, 0);
                }
            }
            // partner-quarter MFMAs
            {
                int i = 0;
                #pragma unroll
                for (int q = 0; q < 4; ++q) {
                    if (q == s) continue;
                    #pragma unroll
                    for (int kk = 0; kk < 2; ++kk) {
                        const h8 av = ap[i++];
                        const int kb = q * 2 + kk;
                        #pragma unroll
                        for (int ti = 0; ti < 4; ++ti) {
                            const h8 b = *(const h8*)&wlds[((w * 32 + ti * 8 + kb) * 64 + l) * 8];
                            acc[ti] = __builtin_amdgcn_mfma_f32_16x16x32_f16(av, b, acc[ti], 0, 0, 0);
                        }
                    }
                }
            }
        }

        // activations: lane holds z for b = lg*4+r, j = s*64 + w*16 + lr
        #pragma unroll
        for (int r = 0; r < 4; ++r) {
            const float ig = fast_sigmoid(acc[0][r]);
            const float fg = fast_sigmoid(acc[1][r]);
            const float gg = fast_tanh(acc[2][r]);
            const float og = fast_sigmoid(acc[3][r]);
            c[r] = fg * c[r] + ig * gg;
            const float hv = og * fast_tanh(c[r]);
            const _Float16 h16 = (_Float16)hv;
            h_sh[nxt][lg * 4 + r][w * 16 + lr] = h16;
            h_all[((size_t)t * 256 + b0 + lg * 4 + r) * 256 + s * 64 + w * 16 + lr] = h16;
        }

        // rotate xg prefetch
        if (t < 255) { xq0 = xqn0; xq1 = xqn1; }

        // ---- publish h[t]: syncthreads drains each thread's vmcnt (stores in
        // L2) and lgkm (h_sh); then ONE release fence + prog store.
        __syncthreads();
        if (tid == 0) {
            __builtin_amdgcn_fence(__ATOMIC_RELEASE, "agent");
            __hip_atomic_store(&prog[bid], (unsigned)(t + 1), __ATOMIC_RELAXED,
                               __HIP_MEMORY_SCOPE_AGENT);
        }
    }
}

// ---------------------------------------------------------------- FC1+FC2
template <typename HT>
__global__ __launch_bounds__(256) void k_fc(
    const HT* __restrict__ h_all, const float* __restrict__ W1,
    const float* __restrict__ b1, const float* __restrict__ W2,
    const float* __restrict__ b2, float* __restrict__ out)
{
    __shared__ __align__(16) float smem[12288];
    float* hsT = smem;
    float* w1T = smem + 4096;
    const int tid = threadIdx.x;
    const int m0 = blockIdx.x * 64;
    const int tx = tid & 15;
    const int ty = tid >> 4;
    const int r0 = ty * 4;
    const int fA = tx * 4;
    const int fB = 64 + tx * 4;
    float acc[4][8] = {};
    for (int kc = 0; kc < 4; ++kc) {
        const int k0 = kc * 64;
        __syncthreads();
        #pragma unroll
        for (int i = 0; i < 4; ++i) {
            const int fid = tid + i * 256;
            const int rr = fid >> 4;
            const int qq = fid & 15;
            const HT* p = &h_all[(size_t)(m0 + rr) * 256 + k0 + qq * 4];
            f4 v;
            if constexpr (std::is_same<HT, float>::value) {
                v = *(const f4*)p;
            } else {
                v[0] = ldf(p); v[1] = ldf(p + 1); v[2] = ldf(p + 2); v[3] = ldf(p + 3);
            }
            #pragma unroll
            for (int cc = 0; cc < 4; ++cc)
                hsT[(qq * 4 + cc) * 64 + rr] = fmaxf(v[cc], 0.f);
        }
        #pragma unroll
        for (int i = 0; i < 8; ++i) {
            const int fid = tid + i * 256;
            const int ff = fid >> 4;
            const int qq = fid & 15;
            const f4 v = *(const f4*)&W1[(size_t)ff * 256 + k0 + qq * 4];
            #pragma unroll
            for (int cc = 0; cc < 4; ++cc)
                w1T[(qq * 4 + cc) * 128 + ff] = v[cc];
        }
        __syncthreads();
        #pragma unroll 4
        for (int kk = 0; kk < 64; ++kk) {
            const f4 aa = *(const f4*)&hsT[kk * 64 + r0];
            const f4 ba = *(const f4*)&w1T[kk * 128 + fA];
            const f4 bb = *(const f4*)&w1T[kk * 128 + fB];
            #pragma unroll
            for (int i = 0; i < 4; ++i) {
                #pragma unroll
                for (int j = 0; j < 4; ++j) {
                    acc[i][j]     = fmaf(aa[i], ba[j], acc[i][j]);
                    acc[i][j + 4] = fmaf(aa[i], bb[j], acc[i][j + 4]);
                }
            }
        }
    }
    __syncthreads();
    float* fc1s = smem;
    #pragma unroll
    for (int j = 0; j < 4; ++j) {
        const float bbA = b1[fA + j];
        const float bbB = b1[fB + j];
        #pragma unroll
        for (int i = 0; i < 4; ++i) {
            fc1s[(r0 + i) * 132 + fA + j] = fmaxf(acc[i][j] + bbA, 0.f);
            fc1s[(r0 + i) * 132 + fB + j] = fmaxf(acc[i][j + 4] + bbB, 0.f);
        }
    }
    __syncthreads();
    const int r  = tid >> 2;
    const int c0 = (tid & 3) * 2;
    float o0 = b2[c0], o1 = b2[c0 + 1];
    #pragma unroll
    for (int fq = 0; fq < 32; ++fq) {
        const f4 p  = *(const f4*)&fc1s[r * 132 + fq * 4];
        const f4 wa = *(const f4*)&W2[(size_t)c0 * 128 + fq * 4];
        const f4 wb = *(const f4*)&W2[(size_t)(c0 + 1) * 128 + fq * 4];
        o0 += p[0] * wa[0] + p[1] * wa[1] + p[2] * wa[2] + p[3] * wa[3];
        o1 += p[0] * wb[0] + p[1] * wb[1] + p[2] * wb[2] + p[3] * wb[3];
    }
    out[(size_t)(m0 + r) * 8 + c0]     = o0;
    out[(size_t)(m0 + r) * 8 + c0 + 1] = o1;
}

// ---------------------------------------------------------------- launch
extern "C" void kernel_launch(void* const* d_in, const int* in_sizes, int n_in,
                              void* d_out, int out_size, void* d_ws, size_t ws_size,
                              hipStream_t stream)
{
    const float* x    = (const float*)d_in[0];
    const float* W_ih = (const float*)d_in[1];
    const float* W_hh = (const float*)d_in[2];
    const float* b_ih = (const float*)d_in[3];
    const float* b_hh = (const float*)d_in[4];
    const float* W1   = (const float*)d_in[5];
    const float* b1   = (const float*)d_in[6];
    const float* W2   = (const float*)d_in[7];
    const float* b2   = (const float*)d_in[8];
    float* out = (float*)d_out;
    char* ws = (char*)d_ws;

    // workspace layout (168,296,704 B -- within the proven 168,300,544 budget)
    _Float16*     xg2   = (_Float16*)ws;                      // 134,217,728 B
    _Float16*     h_all = (_Float16*)(ws + 134217728);        //  33,554,432 B
    _Float16*     Wp    = (_Float16*)(ws + 167772160);        //     524,288 B
    unsigned int* prog  = (unsigned int*)(ws + 168296448);    //         256 B

    k_init<<<1, 64, 0, stream>>>(prog);                       // every launch
    k_pack<<<128, 256, 0, stream>>>(W_hh, Wp);
    k_xg_mfma<<<dim3(8, 512), 256, 0, stream>>>(x, W_ih, b_ih, b_hh, xg2);
    k_lstm_4x<<<64, 256, 0, stream>>>(xg2, Wp, h_all, prog);
    k_fc<_Float16><<<1024, 256, 0, stream>>>(h_all, W1, b1, W2, b2, out);
}

// Round 14
// 2643.693 us; speedup vs baseline: 4.2192x; 4.2192x over previous
//
#include <hip/hip_runtime.h>
#include <type_traits>

// LSTM_69879117906487: T=256,B=256,I=1024,H=256,FC=128,C=8
// Round 14: TWO batch-groups per block (8 blocks x 1024 thr, 16 waves).
// Each W B-fragment is loaded once and feeds MFMAs for BOTH 16-row batch
// groups -> per-batch-row W-supply halves, and the two groups' dependency
// chains interleave (real ILP at 4 waves/SIMD). Cross-CU exchange is
// permanently abandoned (R3: 14us/step, R13: 42us/step -- L2 fence storms).
//   per wave (4 gate-tiles x 8 kb = 32 frags): LDS 7 (kb0, kb1 g<3),
//   stream 25 (kb1 g3 + kb2..7) with 2-slot rotation, <=8 frags in flight.
// waves_per_eu(4,4) pins the reg budget at 128 (R12's silent 64-reg squeeze
// is the known failure mode -- VGPR_Count is the diagnostic).

typedef float    f4    __attribute__((ext_vector_type(4)));
typedef float    f32x4 __attribute__((ext_vector_type(4)));
typedef _Float16 h8    __attribute__((ext_vector_type(8)));
typedef _Float16 h4    __attribute__((ext_vector_type(4)));

__device__ __forceinline__ float ldf(const float* p)    { return *p; }
__device__ __forceinline__ float ldf(const _Float16* p) { return (float)*p; }

__device__ __forceinline__ float fast_sigmoid(float x) {
    return 1.f / (1.f + __expf(-x));
}
// 5-inst tanh: 1 - 2/(1+e^{2x}); saturates correctly for |x| large.
__device__ __forceinline__ float fast_tanh(float x) {
    return 1.f - 2.f / (1.f + __expf(2.f * x));
}

// ---------------------------------------------------------------- W_hh pack
// fi = gt*8 + kb (gt = 16-gate-col tile 0..63). Lane l elem j:
// W_hh[gt*16 + (l&15)][kb*32 + (l>>4)*8 + j]; 16 B/lane.
__global__ __launch_bounds__(256) void k_pack(const float* __restrict__ W_hh,
                                              _Float16* __restrict__ Wp) {
    const int idx = blockIdx.x * 256 + threadIdx.x;
    const int fi = idx >> 6;
    const int l  = idx & 63;
    const int g  = (fi >> 3) * 16 + (l & 15);
    const int k  = (fi & 7) * 32 + ((l >> 4) << 3);
    const float* src = &W_hh[(size_t)g * 256 + k];
    h8 v;
    #pragma unroll
    for (int c = 0; c < 8; ++c) v[c] = (_Float16)src[c];
    *(h8*)&Wp[(size_t)idx * 8] = v;
}

// ---------------------------------------------------------------- xg GEMM (MFMA)
// 128x128 tile, BK=32, 256 thr, bias folded. Epilogue -> 32 B/lane packets:
// addr = (((((t*8+g)*2+G)*16 + w16)*64 + lane)*16 + gate*4, G = (b>>4)&1.
__global__ __launch_bounds__(256) void k_xg_mfma(
    const float* __restrict__ x, const float* __restrict__ W_ih,
    const float* __restrict__ b_ih, const float* __restrict__ b_hh,
    _Float16* __restrict__ xg2)
{
    __shared__ _Float16 As[2][128][40];
    __shared__ _Float16 Bs[2][128][40];
    const int tid = threadIdx.x;
    const int l   = tid & 63;
    const int w   = tid >> 6;
    const int m0  = blockIdx.y * 128;
    const int n0  = blockIdx.x * 128;
    const int wr  = (w >> 1) * 64;
    const int wc  = (w & 1) * 64;
    const int srow = tid >> 2;
    const int skof = (tid & 3) * 8;
    const int lr = l & 15;
    const int lg = l >> 4;

    f32x4 acc[4][4] = {};
    f4 ldA[2][2], ldB[2][2];

    auto XG_LOAD = [&](int kt) {
        const int k0 = kt * 32;
        #pragma unroll
        for (int s = 0; s < 2; ++s) {
            const float* xa = &x[(size_t)(m0 + srow + s * 64) * 1024 + k0 + skof];
            const float* wb = &W_ih[(size_t)(n0 + srow + s * 64) * 1024 + k0 + skof];
            ldA[s][0] = *(const f4*)xa; ldA[s][1] = *(const f4*)(xa + 4);
            ldB[s][0] = *(const f4*)wb; ldB[s][1] = *(const f4*)(wb + 4);
        }
    };
    auto XG_WRITE = [&](int buf) {
        #pragma unroll
        for (int s = 0; s < 2; ++s) {
            h8 va, vb;
            #pragma unroll
            for (int c = 0; c < 8; ++c) {
                va[c] = (_Float16)ldA[s][c >> 2][c & 3];
                vb[c] = (_Float16)ldB[s][c >> 2][c & 3];
            }
            *(h8*)&As[buf][srow + s * 64][skof] = va;
            *(h8*)&Bs[buf][srow + s * 64][skof] = vb;
        }
    };

    XG_LOAD(0);
    XG_WRITE(0);
    __syncthreads();
    for (int kt = 0; kt < 32; ++kt) {
        const int cur = kt & 1;
        if (kt + 1 < 32) XG_LOAD(kt + 1);
        h8 af[4], bf[4];
        #pragma unroll
        for (int mf = 0; mf < 4; ++mf) af[mf] = *(const h8*)&As[cur][wr + mf * 16 + lr][lg * 8];
        #pragma unroll
        for (int nf = 0; nf < 4; ++nf) bf[nf] = *(const h8*)&Bs[cur][wc + nf * 16 + lr][lg * 8];
        #pragma unroll
        for (int mf = 0; mf < 4; ++mf)
            #pragma unroll
            for (int nf = 0; nf < 4; ++nf)
                acc[mf][nf] = __builtin_amdgcn_mfma_f32_16x16x32_f16(af[mf], bf[nf], acc[mf][nf], 0, 0, 0);
        if (kt + 1 < 32) XG_WRITE((kt + 1) & 1);
        __syncthreads();
    }
    #pragma unroll
    for (int nf = 0; nf < 4; ++nf) {
        const int col  = n0 + wc + nf * 16 + lr;
        const float bv = b_ih[col] + b_hh[col];
        const int gate = col >> 8;
        const int w16  = (col >> 4) & 15;
        #pragma unroll
        for (int mf = 0; mf < 4; ++mf) {
            const int rowb = m0 + wr + mf * 16 + lg * 4;
            const int tt = rowb >> 8;
            const int b  = rowb & 255;
            const int g8 = b >> 5;
            const int G  = (b >> 4) & 1;
            h4 pk;
            #pragma unroll
            for (int r = 0; r < 4; ++r) pk[r] = (_Float16)(acc[mf][nf][r] + bv);
            *(h4*)&xg2[(((((size_t)tt * 8 + g8) * 2 + G) * 16 + w16) * 64 + l) * 16 + gate * 4] = pk;
        }
    }
}

// ---------------------------------------------------------------- recurrence
// 8 blocks x 1024 thr (16 waves, 4/SIMD). Block g: batch [32g, 32g+32) as two
// groups G=0,1. Wave w owns j in [16w, 16w+16) x all 4 gates.
// fgid(gate,kb) = (gate*16 + w)*8 + kb (same Wp layout as k_pack).
__global__
__attribute__((amdgpu_flat_work_group_size(1024, 1024), amdgpu_waves_per_eu(4, 4)))
void k_lstm_2g(const _Float16* __restrict__ xg2, const _Float16* __restrict__ Wp,
               _Float16* __restrict__ h_all)
{
    __shared__ _Float16 wlds[16 * 7 * 512];     // 114,688 B
    __shared__ _Float16 h_sh[2][2][16][270];    //  34,560 B (G, buf, row, col)
    const int tid = threadIdx.x;
    const int w  = tid >> 6;        // 0..15
    const int l  = tid & 63;
    const int lr = l & 15;
    const int lg = l >> 4;
    const int g  = blockIdx.x;      // 0..7
    const int b0 = g * 32;

    auto fgid = [&](int gate, int kb) { return (gate * 16 + w) * 8 + kb; };
    auto ldfrag = [&](int gate, int kb) {
        return *(const h8*)&Wp[((size_t)fgid(gate, kb) * 64 + l) * 8];
    };

    // ---- LDS-resident W: kb0 all gates (4) + kb1 gates 0..2 (3)
    #pragma unroll
    for (int gate = 0; gate < 4; ++gate)
        *(h8*)&wlds[((w * 7 + gate) * 64 + l) * 8] = ldfrag(gate, 0);
    #pragma unroll
    for (int gate = 0; gate < 3; ++gate)
        *(h8*)&wlds[((w * 7 + 4 + gate) * 64 + l) * 8] = ldfrag(gate, 1);

    {   // zero h buffers
        _Float16* p = &h_sh[0][0][0][0];
        for (int i = tid; i < 2 * 2 * 16 * 270; i += 1024) p[i] = (_Float16)0.f;
    }
    __syncthreads();

    float c[2][4] = {};

    for (int t = 0; t < 256; ++t) {
        const int cur = t & 1;
        const int nxt = cur ^ 1;

        // xg packets for both groups (32 B/lane each, coalesced)
        const size_t E0 = ((((size_t)t * 8 + g) * 2 + 0) * 16 + w) * 64 * 16 + (size_t)l * 16;
        const size_t E1 = E0 + (size_t)16 * 64 * 16;
        h8 xa0 = *(const h8*)&xg2[E0];
        h8 xa1 = *(const h8*)&xg2[E0 + 8];
        h8 xb0 = *(const h8*)&xg2[E1];
        h8 xb1 = *(const h8*)&xg2[E1 + 8];

        // acc init = xg (MFMA C-operand accumulates the matmul on top)
        f32x4 acc[2][4];
        #pragma unroll
        for (int gate = 0; gate < 4; ++gate) {
            #pragma unroll
            for (int r = 0; r < 4; ++r) {
                const int v = gate * 4 + r;   // 0..15
                acc[0][gate][r] = (float)((v < 8) ? xa0[v] : xa1[v - 8]);
                acc[1][gate][r] = (float)((v < 8) ? xb0[v] : xb1[v - 8]);
            }
        }

        // streamed W: 25 frags/wave, 2-slot rotation (anti-hoist via soff)
        unsigned soff = 0;
        asm volatile("" : "+v"(soff));
        auto ldstream = [&](int gate, int kb) {
            return *(const h8*)&Wp[((size_t)fgid(gate, kb) * 64 + l) * 8 + soff];
        };

        h8 s1g3 = ldstream(3, 1);
        h8 sv0[4], sv1[4];
        #pragma unroll
        for (int gate = 0; gate < 4; ++gate) sv0[gate] = ldstream(gate, 2);
        #pragma unroll
        for (int gate = 0; gate < 4; ++gate) sv1[gate] = ldstream(gate, 3);

        // kb0: LDS B, both groups share each B-frag
        {
            const h8 a0 = *(const h8*)&h_sh[0][cur][lr][0 * 32 + lg * 8];
            const h8 a1 = *(const h8*)&h_sh[1][cur][lr][0 * 32 + lg * 8];
            #pragma unroll
            for (int gate = 0; gate < 4; ++gate) {
                const h8 b = *(const h8*)&wlds[((w * 7 + gate) * 64 + l) * 8];
                acc[0][gate] = __builtin_amdgcn_mfma_f32_16x16x32_f16(a0, b, acc[0][gate], 0, 0, 0);
                acc[1][gate] = __builtin_amdgcn_mfma_f32_16x16x32_f16(a1, b, acc[1][gate], 0, 0, 0);
            }
        }
        // kb1: LDS x3 + streamed x1
        {
            const h8 a0 = *(const h8*)&h_sh[0][cur][lr][1 * 32 + lg * 8];
            const h8 a1 = *(const h8*)&h_sh[1][cur][lr][1 * 32 + lg * 8];
            #pragma unroll
            for (int gate = 0; gate < 4; ++gate) {
                const h8 b = (gate < 3) ? *(const h8*)&wlds[((w * 7 + 4 + gate) * 64 + l) * 8]
                                        : s1g3;
                acc[0][gate] = __builtin_amdgcn_mfma_f32_16x16x32_f16(a0, b, acc[0][gate], 0, 0, 0);
                acc[1][gate] = __builtin_amdgcn_mfma_f32_16x16x32_f16(a1, b, acc[1][gate], 0, 0, 0);
            }
        }
        // kb2..7: rotate sv0/sv1, refill 2 kb ahead
        #pragma unroll
        for (int kb = 2; kb < 8; ++kb) {
            const h8 a0 = *(const h8*)&h_sh[0][cur][lr][kb * 32 + lg * 8];
            const h8 a1 = *(const h8*)&h_sh[1][cur][lr][kb * 32 + lg * 8];
            if (kb & 1) {
                #pragma unroll
                for (int gate = 0; gate < 4; ++gate) {
                    acc[0][gate] = __builtin_amdgcn_mfma_f32_16x16x32_f16(a0, sv1[gate], acc[0][gate], 0, 0, 0);
                    acc[1][gate] = __builtin_amdgcn_mfma_f32_16x16x32_f16(a1, sv1[gate], acc[1][gate], 0, 0, 0);
                }
                if (kb + 2 < 8) {
                    #pragma unroll
                    for (int gate = 0; gate < 4; ++gate) sv1[gate] = ldstream(gate, kb + 2);
                }
            } else {
                #pragma unroll
                for (int gate = 0; gate < 4; ++gate) {
                    acc[0][gate] = __builtin_amdgcn_mfma_f32_16x16x32_f16(a0, sv0[gate], acc[0][gate], 0, 0, 0);
                    acc[1][gate] = __builtin_amdgcn_mfma_f32_16x16x32_f16(a1, sv0[gate], acc[1][gate], 0, 0, 0);
                }
                if (kb + 2 < 8) {
                    #pragma unroll
                    for (int gate = 0; gate < 4; ++gate) sv0[gate] = ldstream(gate, kb + 2);
                }
            }
        }

        // activations: lane holds z for b = b0+16G+lg*4+r, j = 16w+lr
        #pragma unroll
        for (int G = 0; G < 2; ++G) {
            #pragma unroll
            for (int r = 0; r < 4; ++r) {
                const float ig = fast_sigmoid(acc[G][0][r]);
                const float fg = fast_sigmoid(acc[G][1][r]);
                const float gg = fast_tanh(acc[G][2][r]);
                const float og = fast_sigmoid(acc[G][3][r]);
                c[G][r] = fg * c[G][r] + ig * gg;
                const float hv = og * fast_tanh(c[G][r]);
                const _Float16 h16 = (_Float16)hv;
                h_sh[G][nxt][lg * 4 + r][w * 16 + lr] = h16;
                h_all[((size_t)t * 256 + b0 + G * 16 + lg * 4 + r) * 256 + w * 16 + lr] = h16;
            }
        }

        // raw barrier: drain LDS only; global stores/loads flow across it.
        asm volatile("s_waitcnt lgkmcnt(0)" ::: "memory");
        __builtin_amdgcn_s_barrier();
        __builtin_amdgcn_sched_barrier(0);
    }
}

// ---------------------------------------------------------------- FC1+FC2
template <typename HT>
__global__ __launch_bounds__(256) void k_fc(
    const HT* __restrict__ h_all, const float* __restrict__ W1,
    const float* __restrict__ b1, const float* __restrict__ W2,
    const float* __restrict__ b2, float* __restrict__ out)
{
    __shared__ __align__(16) float smem[12288];
    float* hsT = smem;
    float* w1T = smem + 4096;
    const int tid = threadIdx.x;
    const int m0 = blockIdx.x * 64;
    const int tx = tid & 15;
    const int ty = tid >> 4;
    const int r0 = ty * 4;
    const int fA = tx * 4;
    const int fB = 64 + tx * 4;
    float acc[4][8] = {};
    for (int kc = 0; kc < 4; ++kc) {
        const int k0 = kc * 64;
        __syncthreads();
        #pragma unroll
        for (int i = 0; i < 4; ++i) {
            const int fid = tid + i * 256;
            const int rr = fid >> 4;
            const int qq = fid & 15;
            const HT* p = &h_all[(size_t)(m0 + rr) * 256 + k0 + qq * 4];
            f4 v;
            if constexpr (std::is_same<HT, float>::value) {
                v = *(const f4*)p;
            } else {
                v[0] = ldf(p); v[1] = ldf(p + 1); v[2] = ldf(p + 2); v[3] = ldf(p + 3);
            }
            #pragma unroll
            for (int cc = 0; cc < 4; ++cc)
                hsT[(qq * 4 + cc) * 64 + rr] = fmaxf(v[cc], 0.f);
        }
        #pragma unroll
        for (int i = 0; i < 8; ++i) {
            const int fid = tid + i * 256;
            const int ff = fid >> 4;
            const int qq = fid & 15;
            const f4 v = *(const f4*)&W1[(size_t)ff * 256 + k0 + qq * 4];
            #pragma unroll
            for (int cc = 0; cc < 4; ++cc)
                w1T[(qq * 4 + cc) * 128 + ff] = v[cc];
        }
        __syncthreads();
        #pragma unroll 4
        for (int kk = 0; kk < 64; ++kk) {
            const f4 aa = *(const f4*)&hsT[kk * 64 + r0];
            const f4 ba = *(const f4*)&w1T[kk * 128 + fA];
            const f4 bb = *(const f4*)&w1T[kk * 128 + fB];
            #pragma unroll
            for (int i = 0; i < 4; ++i) {
                #pragma unroll
                for (int j = 0; j < 4; ++j) {
                    acc[i][j]     = fmaf(aa[i], ba[j], acc[i][j]);
                    acc[i][j + 4] = fmaf(aa[i], bb[j], acc[i][j + 4]);
                }
            }
        }
    }
    __syncthreads();
    float* fc1s = smem;
    #pragma unroll
    for (int j = 0; j < 4; ++j) {
        const float bbA = b1[fA + j];
        const float bbB = b1[fB + j];
        #pragma unroll
        for (int i = 0; i < 4; ++i) {
            fc1s[(r0 + i) * 132 + fA + j] = fmaxf(acc[i][j] + bbA, 0.f);
            fc1s[(r0 + i) * 132 + fB + j] = fmaxf(acc[i][j + 4] + bbB, 0.f);
        }
    }
    __syncthreads();
    const int r  = tid >> 2;
    const int c0 = (tid & 3) * 2;
    float o0 = b2[c0], o1 = b2[c0 + 1];
    #pragma unroll
    for (int fq = 0; fq < 32; ++fq) {
        const f4 p  = *(const f4*)&fc1s[r * 132 + fq * 4];
        const f4 wa = *(const f4*)&W2[(size_t)c0 * 128 + fq * 4];
        const f4 wb = *(const f4*)&W2[(size_t)(c0 + 1) * 128 + fq * 4];
        o0 += p[0] * wa[0] + p[1] * wa[1] + p[2] * wa[2] + p[3] * wa[3];
        o1 += p[0] * wb[0] + p[1] * wb[1] + p[2] * wb[2] + p[3] * wb[3];
    }
    out[(size_t)(m0 + r) * 8 + c0]     = o0;
    out[(size_t)(m0 + r) * 8 + c0 + 1] = o1;
}

// ---------------------------------------------------------------- launch
extern "C" void kernel_launch(void* const* d_in, const int* in_sizes, int n_in,
                              void* d_out, int out_size, void* d_ws, size_t ws_size,
                              hipStream_t stream)
{
    const float* x    = (const float*)d_in[0];
    const float* W_ih = (const float*)d_in[1];
    const float* W_hh = (const float*)d_in[2];
    const float* b_ih = (const float*)d_in[3];
    const float* b_hh = (const float*)d_in[4];
    const float* W1   = (const float*)d_in[5];
    const float* b1   = (const float*)d_in[6];
    const float* W2   = (const float*)d_in[7];
    const float* b2   = (const float*)d_in[8];
    float* out = (float*)d_out;
    char* ws = (char*)d_ws;

    // workspace layout (168,296,448 B)
    _Float16* xg2   = (_Float16*)ws;                          // 134,217,728 B
    _Float16* h_all = (_Float16*)(ws + 134217728);            //  33,554,432 B
    _Float16* Wp    = (_Float16*)(ws + 167772160);            //     524,288 B

    k_pack<<<128, 256, 0, stream>>>(W_hh, Wp);
    k_xg_mfma<<<dim3(8, 512), 256, 0, stream>>>(x, W_ih, b_ih, b_hh, xg2);
    k_lstm_2g<<<8, 1024, 0, stream>>>(xg2, Wp, h_all);
    k_fc<_Float16><<<1024, 256, 0, stream>>>(h_all, W1, b1, W2, b2, out);
}

// Round 15
// 2086.351 us; speedup vs baseline: 5.3463x; 1.2671x over previous
//
#include <hip/hip_runtime.h>
#include <type_traits>

// LSTM_69879117906487: T=256,B=256,I=1024,H=256,FC=128,C=8
// Round 15: recurrence = full-W LDS-window streaming via global_load_lds.
// R9-R12 showed register-bounded load depth serializes the W stream (~14k
// cyc/step vs ~8k of pure fill). global_load_lds holds NOTHING in VGPRs ->
// unbounded outstanding loads. Wave-PRIVATE windows (8KB x2 double-buffer per
// wave) need NO barrier for W -- only counted s_waitcnt vmcnt within the wave:
//   step start: vmcnt(16)  (xq+stores retired; chunks 0,1 in flight)
//   chunk cb:   vmcnt(8)   (cb done; cb+1 in flight), cb==7: vmcnt(0)
//   next step's chunks 0,1 + xq issued BEFORE the raw barrier (lgkm-only).
// Everything else (math, layouts, k_xg/k_fc) = R9 proven numerics.

typedef float    f4    __attribute__((ext_vector_type(4)));
typedef float    f32x4 __attribute__((ext_vector_type(4)));
typedef _Float16 h8    __attribute__((ext_vector_type(8)));
typedef _Float16 h4    __attribute__((ext_vector_type(4)));

__device__ __forceinline__ float ldf(const float* p)    { return *p; }
__device__ __forceinline__ float ldf(const _Float16* p) { return (float)*p; }

__device__ __forceinline__ float fast_sigmoid(float x) {
    return 1.f / (1.f + __expf(-x));
}
__device__ __forceinline__ float fast_tanh(float x) {
    const float e = __expf(-2.f * fabsf(x));
    const float t = (1.f - e) / (1.f + e);
    return copysignf(t, x);
}

// counted vmcnt wait + rule-18 fence (literal N via token paste)
#define WAITVM(n) do { asm volatile("s_waitcnt vmcnt(" #n ")" ::: "memory"); \
                       __builtin_amdgcn_sched_barrier(0); } while (0)

// 16B/lane global -> LDS (wave-uniform base + lane*16), no VGPR round-trip
__device__ __forceinline__ void stage16(const _Float16* g, _Float16* l) {
    __builtin_amdgcn_global_load_lds(
        (const __attribute__((address_space(1))) void*)g,
        (__attribute__((address_space(3))) void*)l, 16, 0, 0);
}

// ---------------------------------------------------------------- W_hh pack
// fi = gt*8 + kb (gt = 16-gate-col tile 0..63). Lane l elem j:
// W_hh[gt*16 + (l&15)][kb*32 + (l>>4)*8 + j]; frag = 1 KB contiguous.
__global__ __launch_bounds__(256) void k_pack(const float* __restrict__ W_hh,
                                              _Float16* __restrict__ Wp) {
    const int idx = blockIdx.x * 256 + threadIdx.x;
    const int fi = idx >> 6;
    const int l  = idx & 63;
    const int g  = (fi >> 3) * 16 + (l & 15);
    const int k  = (fi & 7) * 32 + ((l >> 4) << 3);
    const float* src = &W_hh[(size_t)g * 256 + k];
    h8 v;
    #pragma unroll
    for (int c = 0; c < 8; ++c) v[c] = (_Float16)src[c];
    *(h8*)&Wp[(size_t)idx * 8] = v;
}

// ---------------------------------------------------------------- xg GEMM (MFMA)
// 128x128 tile, BK=32, 256 thr, bias folded. Epilogue -> 64 B/lane packets:
// base = (((t*16+gb)*8 + w8)*64 + lane)*32, elem = gate*8 + jt*4 + r.
__global__ __launch_bounds__(256) void k_xg_mfma(
    const float* __restrict__ x, const float* __restrict__ W_ih,
    const float* __restrict__ b_ih, const float* __restrict__ b_hh,
    _Float16* __restrict__ xg2)
{
    __shared__ _Float16 As[2][128][40];
    __shared__ _Float16 Bs[2][128][40];
    const int tid = threadIdx.x;
    const int l   = tid & 63;
    const int w   = tid >> 6;
    const int m0  = blockIdx.y * 128;
    const int n0  = blockIdx.x * 128;
    const int wr  = (w >> 1) * 64;
    const int wc  = (w & 1) * 64;
    const int srow = tid >> 2;
    const int skof = (tid & 3) * 8;
    const int lr = l & 15;
    const int lg = l >> 4;

    f32x4 acc[4][4] = {};
    f4 ldA[2][2], ldB[2][2];

    auto XG_LOAD = [&](int kt) {
        const int k0 = kt * 32;
        #pragma unroll
        for (int s = 0; s < 2; ++s) {
            const float* xa = &x[(size_t)(m0 + srow + s * 64) * 1024 + k0 + skof];
            const float* wb = &W_ih[(size_t)(n0 + srow + s * 64) * 1024 + k0 + skof];
            ldA[s][0] = *(const f4*)xa; ldA[s][1] = *(const f4*)(xa + 4);
            ldB[s][0] = *(const f4*)wb; ldB[s][1] = *(const f4*)(wb + 4);
        }
    };
    auto XG_WRITE = [&](int buf) {
        #pragma unroll
        for (int s = 0; s < 2; ++s) {
            h8 va, vb;
            #pragma unroll
            for (int c = 0; c < 8; ++c) {
                va[c] = (_Float16)ldA[s][c >> 2][c & 3];
                vb[c] = (_Float16)ldB[s][c >> 2][c & 3];
            }
            *(h8*)&As[buf][srow + s * 64][skof] = va;
            *(h8*)&Bs[buf][srow + s * 64][skof] = vb;
        }
    };

    XG_LOAD(0);
    XG_WRITE(0);
    __syncthreads();
    for (int kt = 0; kt < 32; ++kt) {
        const int cur = kt & 1;
        if (kt + 1 < 32) XG_LOAD(kt + 1);
        h8 af[4], bf[4];
        #pragma unroll
        for (int mf = 0; mf < 4; ++mf) af[mf] = *(const h8*)&As[cur][wr + mf * 16 + lr][lg * 8];
        #pragma unroll
        for (int nf = 0; nf < 4; ++nf) bf[nf] = *(const h8*)&Bs[cur][wc + nf * 16 + lr][lg * 8];
        #pragma unroll
        for (int mf = 0; mf < 4; ++mf)
            #pragma unroll
            for (int nf = 0; nf < 4; ++nf)
                acc[mf][nf] = __builtin_amdgcn_mfma_f32_16x16x32_f16(af[mf], bf[nf], acc[mf][nf], 0, 0, 0);
        if (kt + 1 < 32) XG_WRITE((kt + 1) & 1);
        __syncthreads();
    }
    #pragma unroll
    for (int nf = 0; nf < 4; ++nf) {
        const int col  = n0 + wc + nf * 16 + lr;
        const float bv = b_ih[col] + b_hh[col];
        const int gate = col >> 8;
        const int w8   = (col >> 5) & 7;
        const int jt   = (col >> 4) & 1;
        #pragma unroll
        for (int mf = 0; mf < 4; ++mf) {
            const int rowb = m0 + wr + mf * 16 + lg * 4;
            const int tt = rowb >> 8;
            const int gb = (rowb >> 4) & 15;
            h4 pk;
            #pragma unroll
            for (int r = 0; r < 4; ++r) pk[r] = (_Float16)(acc[mf][nf][r] + bv);
            *(h4*)&xg2[((((size_t)tt * 16 + gb) * 8 + w8) * 64 + l) * 32 + gate * 8 + jt * 4] = pk;
        }
    }
}

// ---------------------------------------------------------------- recurrence
// 16 blocks x 512 thr (8 waves, 2/SIMD). Wave w owns j in [32w,32w+32):
// 8 tiles ti = gate*2 + jt, 8 kb -> 64 frags, ALL streamed per step through
// the wave's private LDS window (2 bufs x 8 frags x 1 KB).
__global__ __launch_bounds__(512, 2) void k_lstm_st(
    const _Float16* __restrict__ xg2, const _Float16* __restrict__ Wp,
    _Float16* __restrict__ h_all)
{
    __shared__ _Float16 wwin[8 * 2 * 8 * 512];   // 131,072 B
    __shared__ _Float16 h_sh[2][16][264];        //  16,896 B (total 147,968)
    const int tid = threadIdx.x;
    const int w  = tid >> 6;       // 0..7
    const int l  = tid & 63;
    const int lr = l & 15;
    const int lg = l >> 4;
    const int g  = blockIdx.x;
    const int b0 = g * 16;

    auto fgid = [&](int ti, int kb) {   // ti = gate*2+jt -> gt = gate*16 + w*2 + jt
        return (((ti >> 1) * 16 + w * 2 + (ti & 1)) * 8 + kb);
    };
    auto STAGE = [&](int kb, int buf) {
        #pragma unroll
        for (int ti = 0; ti < 8; ++ti)
            stage16(&Wp[((size_t)fgid(ti, kb) * 64 + l) * 8],
                    &wwin[((w * 2 + buf) * 8 + ti) * 512]);
    };

    {   // zero h buffers
        _Float16* p = &h_sh[0][0][0];
        for (int i = tid; i < 2 * 16 * 264; i += 512) p[i] = (_Float16)0.f;
    }
    __syncthreads();

    float c[8];
    #pragma unroll
    for (int i = 0; i < 8; ++i) c[i] = 0.f;

    // prologue: xg[0] packet + chunks 0,1 in flight
    h8 xq[4];
    {
        const size_t E0 = (((size_t)g * 8 + w) * 64 + l) * 32;
        #pragma unroll
        for (int q = 0; q < 4; ++q) xq[q] = *(const h8*)&xg2[E0 + q * 8];
    }
    STAGE(0, 0);
    STAGE(1, 1);

    for (int t = 0; t < 256; ++t) {
        const int cur = t & 1;
        const int nxt = cur ^ 1;

        // xq (and prev stores) retired; chunks 0,1 (16 loads) may stay in flight
        WAITVM(16);

        // acc init = xg (MFMA C-operand accumulates the matmul on top)
        f32x4 acc[8];
        #pragma unroll
        for (int ti = 0; ti < 8; ++ti) {
            #pragma unroll
            for (int r = 0; r < 4; ++r)
                acc[ti][r] = (float)xq[ti >> 1][(ti & 1) * 4 + r];
        }

        // 8 chunks: consume kb==cb from buf (cb&1); refill 2 ahead
        #pragma unroll
        for (int cb = 0; cb < 8; ++cb) {
            if (cb < 7) WAITVM(8); else WAITVM(0);
            const h8 av = *(const h8*)&h_sh[cur][lr][cb * 32 + lg * 8];
            #pragma unroll
            for (int ti = 0; ti < 8; ++ti) {
                const h8 b = *(const h8*)&wwin[((w * 2 + (cb & 1)) * 8 + ti) * 512 + l * 8];
                acc[ti] = __builtin_amdgcn_mfma_f32_16x16x32_f16(av, b, acc[ti], 0, 0, 0);
            }
            if (cb + 2 < 8) {
                __builtin_amdgcn_sched_barrier(0);   // keep STAGE after consumption
                STAGE(cb + 2, cb & 1);
            }
        }

        // next step's xg packet (issued first -> retires first at next WAITVM(16))
        h8 xqn[4];
        if (t < 255) {
            const size_t En = ((((size_t)(t + 1) * 16 + g) * 8 + w) * 64 + l) * 32;
            #pragma unroll
            for (int q = 0; q < 4; ++q) xqn[q] = *(const h8*)&xg2[En + q * 8];
        }

        // activations: lane holds z for b = lg*4+r, j = w*32+jt*16+lr, all gates
        #pragma unroll
        for (int jt = 0; jt < 2; ++jt) {
            #pragma unroll
            for (int r = 0; r < 4; ++r) {
                const float ig = fast_sigmoid(acc[0 * 2 + jt][r]);
                const float fg = fast_sigmoid(acc[1 * 2 + jt][r]);
                const float gg = fast_tanh(acc[2 * 2 + jt][r]);
                const float og = fast_sigmoid(acc[3 * 2 + jt][r]);
                const int ci = jt * 4 + r;
                c[ci] = fg * c[ci] + ig * gg;
                const float hv = og * fast_tanh(c[ci]);
                const _Float16 h16 = (_Float16)hv;
                h_sh[nxt][lg * 4 + r][w * 32 + jt * 16 + lr] = h16;
                h_all[((size_t)t * 256 + b0 + lg * 4 + r) * 256 + w * 32 + jt * 16 + lr] = h16;
            }
        }

        // next step's chunks 0,1 into the (now consumed) windows, then rotate xq
        if (t < 255) {
            STAGE(0, 0);
            STAGE(1, 1);
            #pragma unroll
            for (int q = 0; q < 4; ++q) xq[q] = xqn[q];
        }

        // raw barrier: drain LDS only; global loads/stores flow across it
        asm volatile("s_waitcnt lgkmcnt(0)" ::: "memory");
        __builtin_amdgcn_s_barrier();
        __builtin_amdgcn_sched_barrier(0);
    }
}

// ---------------------------------------------------------------- FC1+FC2
template <typename HT>
__global__ __launch_bounds__(256) void k_fc(
    const HT* __restrict__ h_all, const float* __restrict__ W1,
    const float* __restrict__ b1, const float* __restrict__ W2,
    const float* __restrict__ b2, float* __restrict__ out)
{
    __shared__ __align__(16) float smem[12288];
    float* hsT = smem;
    float* w1T = smem + 4096;
    const int tid = threadIdx.x;
    const int m0 = blockIdx.x * 64;
    const int tx = tid & 15;
    const int ty = tid >> 4;
    const int r0 = ty * 4;
    const int fA = tx * 4;
    const int fB = 64 + tx * 4;
    float acc[4][8] = {};
    for (int kc = 0; kc < 4; ++kc) {
        const int k0 = kc * 64;
        __syncthreads();
        #pragma unroll
        for (int i = 0; i < 4; ++i) {
            const int fid = tid + i * 256;
            const int rr = fid >> 4;
            const int qq = fid & 15;
            const HT* p = &h_all[(size_t)(m0 + rr) * 256 + k0 + qq * 4];
            f4 v;
            if constexpr (std::is_same<HT, float>::value) {
                v = *(const f4*)p;
            } else {
                v[0] = ldf(p); v[1] = ldf(p + 1); v[2] = ldf(p + 2); v[3] = ldf(p + 3);
            }
            #pragma unroll
            for (int cc = 0; cc < 4; ++cc)
                hsT[(qq * 4 + cc) * 64 + rr] = fmaxf(v[cc], 0.f);
        }
        #pragma unroll
        for (int i = 0; i < 8; ++i) {
            const int fid = tid + i * 256;
            const int ff = fid >> 4;
            const int qq = fid & 15;
            const f4 v = *(const f4*)&W1[(size_t)ff * 256 + k0 + qq * 4];
            #pragma unroll
            for (int cc = 0; cc < 4; ++cc)
                w1T[(qq * 4 + cc) * 128 + ff] = v[cc];
        }
        __syncthreads();
        #pragma unroll 4
        for (int kk = 0; kk < 64; ++kk) {
            const f4 aa = *(const f4*)&hsT[kk * 64 + r0];
            const f4 ba = *(const f4*)&w1T[kk * 128 + fA];
            const f4 bb = *(const f4*)&w1T[kk * 128 + fB];
            #pragma unroll
            for (int i = 0; i < 4; ++i) {
                #pragma unroll
                for (int j = 0; j < 4; ++j) {
                    acc[i][j]     = fmaf(aa[i], ba[j], acc[i][j]);
                    acc[i][j + 4] = fmaf(aa[i], bb[j], acc[i][j + 4]);
                }
            }
        }
    }
    __syncthreads();
    float* fc1s = smem;
    #pragma unroll
    for (int j = 0; j < 4; ++j) {
        const float bbA = b1[fA + j];
        const float bbB = b1[fB + j];
        #pragma unroll
        for (int i = 0; i < 4; ++i) {
            fc1s[(r0 + i) * 132 + fA + j] = fmaxf(acc[i][j] + bbA, 0.f);
            fc1s[(r0 + i) * 132 + fB + j] = fmaxf(acc[i][j + 4] + bbB, 0.f);
        }
    }
    __syncthreads();
    const int r  = tid >> 2;
    const int c0 = (tid & 3) * 2;
    float o0 = b2[c0], o1 = b2[c0 + 1];
    #pragma unroll
    for (int fq = 0; fq < 32; ++fq) {
        const f4 p  = *(const f4*)&fc1s[r * 132 + fq * 4];
        const f4 wa = *(const f4*)&W2[(size_t)c0 * 128 + fq * 4];
        const f4 wb = *(const f4*)&W2[(size_t)(c0 + 1) * 128 + fq * 4];
        o0 += p[0] * wa[0] + p[1] * wa[1] + p[2] * wa[2] + p[3] * wa[3];
        o1 += p[0] * wb[0] + p[1] * wb[1] + p[2] * wb[2] + p[3] * wb[3];
    }
    out[(size_t)(m0 + r) * 8 + c0]     = o0;
    out[(size_t)(m0 + r) * 8 + c0 + 1] = o1;
}

// ---------------------------------------------------------------- launch
extern "C" void kernel_launch(void* const* d_in, const int* in_sizes, int n_in,
                              void* d_out, int out_size, void* d_ws, size_t ws_size,
                              hipStream_t stream)
{
    const float* x    = (const float*)d_in[0];
    const float* W_ih = (const float*)d_in[1];
    const float* W_hh = (const float*)d_in[2];
    const float* b_ih = (const float*)d_in[3];
    const float* b_hh = (const float*)d_in[4];
    const float* W1   = (const float*)d_in[5];
    const float* b1   = (const float*)d_in[6];
    const float* W2   = (const float*)d_in[7];
    const float* b2   = (const float*)d_in[8];
    float* out = (float*)d_out;
    char* ws = (char*)d_ws;

    // workspace layout (168,296,448 B)
    _Float16* xg2   = (_Float16*)ws;                          // 134,217,728 B
    _Float16* h_all = (_Float16*)(ws + 134217728);            //  33,554,432 B
    _Float16* Wp    = (_Float16*)(ws + 167772160);            //     524,288 B

    k_pack<<<128, 256, 0, stream>>>(W_hh, Wp);
    k_xg_mfma<<<dim3(8, 512), 256, 0, stream>>>(x, W_ih, b_ih, b_hh, xg2);
    k_lstm_st<<<16, 512, 0, stream>>>(xg2, Wp, h_all);
    k_fc<_Float16><<<1024, 256, 0, stream>>>(h_all, W1, b1, W2, b2, out);
}

// Round 16
// 1897.000 us; speedup vs baseline: 5.8800x; 1.0998x over previous
//
#include <hip/hip_runtime.h>
#include <type_traits>

// LSTM_69879117906487: T=256,B=256,I=1024,H=256,FC=128,C=8
// Round 16: best-known recurrence (R9's k_lstm_8w, 1508us -- the floor of a
// 7-structure plateau at ~14.5-15.1k cyc/step) + XCD-swizzled k_xg_mfma.
// k_xg's grid dispatched x-tile-sharing blocks onto 8 DIFFERENT XCDs ->
// x re-fetched into 8 L2s (~2.1 GB HBM). Bijective swizzle (T1, m204 form,
// 4096%8==0) makes each m-slab's 8 n-tiles consecutive on ONE XCD -> x
// fetched once per tile. Pure index remap, correctness-neutral.

typedef float    f4    __attribute__((ext_vector_type(4)));
typedef float    f32x4 __attribute__((ext_vector_type(4)));
typedef _Float16 h8    __attribute__((ext_vector_type(8)));
typedef _Float16 h4    __attribute__((ext_vector_type(4)));

__device__ __forceinline__ float ldf(const float* p)    { return *p; }
__device__ __forceinline__ float ldf(const _Float16* p) { return (float)*p; }

__device__ __forceinline__ float fast_sigmoid(float x) {
    return 1.f / (1.f + __expf(-x));
}
__device__ __forceinline__ float fast_tanh(float x) {
    const float e = __expf(-2.f * fabsf(x));
    const float t = (1.f - e) / (1.f + e);
    return copysignf(t, x);
}

// ---------------------------------------------------------------- bias
__global__ __launch_bounds__(256) void k_bias(const float* __restrict__ b_ih,
                                              const float* __restrict__ b_hh,
                                              float* __restrict__ bias) {
    const int i = blockIdx.x * 256 + threadIdx.x;
    if (i < 1024) bias[i] = b_ih[i] + b_hh[i];
}

// ---------------------------------------------------------------- W_hh pack
// fi = gt*8 + kb (gt = 16-gate tile 0..63, kb = 32-k block 0..7).
// Lane l elem j: W_hh[gt*16 + (l&15)][kb*32 + (l>>4)*8 + j]; 16 B/lane.
__global__ __launch_bounds__(256) void k_pack(const float* __restrict__ W_hh,
                                              _Float16* __restrict__ Wp) {
    const int idx = blockIdx.x * 256 + threadIdx.x;
    const int fi = idx >> 6;
    const int l  = idx & 63;
    const int g  = (fi >> 3) * 16 + (l & 15);
    const int k  = (fi & 7) * 32 + ((l >> 4) << 3);
    const float* src = &W_hh[(size_t)g * 256 + k];
    h8 v;
    #pragma unroll
    for (int c = 0; c < 8; ++c) v[c] = (_Float16)src[c];
    *(h8*)&Wp[(size_t)idx * 8] = v;
}

// ---------------------------------------------------------------- xg GEMM (MFMA)
// 128x128 tile, BK=32, 256 thr. XCD-swizzled block mapping (see header).
// Epilogue -> xg2 packets: base = (((t*16+g)*8 + w8)*64 + lane)*32,
// elem = gate*8 + jt*4 + r.
__global__ __launch_bounds__(256) void k_xg_mfma(
    const float* __restrict__ x, const float* __restrict__ W_ih,
    const float* __restrict__ bias, _Float16* __restrict__ xg2)
{
    __shared__ _Float16 As[2][128][40];
    __shared__ _Float16 Bs[2][128][40];
    const int tid = threadIdx.x;
    const int l   = tid & 63;
    const int w   = tid >> 6;
    // bijective XCD swizzle: nwg=4096, 4096%8==0 -> swz=(bid&7)*512+(bid>>3).
    // XCD c (= bid%8 under round-robin) then owns consecutive swz in
    // [c*512,(c+1)*512): n cycles fastest within one m-slab -> x-tile L2 reuse.
    const int bid = blockIdx.y * 8 + blockIdx.x;
    const int swz = (bid & 7) * 512 + (bid >> 3);
    const int m0  = (swz >> 3) * 128;
    const int n0  = (swz & 7) * 128;
    const int wr  = (w >> 1) * 64;
    const int wc  = (w & 1) * 64;
    const int srow = tid >> 2;
    const int skof = (tid & 3) * 8;
    const int lr = l & 15;
    const int lg = l >> 4;

    f32x4 acc[4][4] = {};
    f4 ldA[2][2], ldB[2][2];

    auto XG_LOAD = [&](int kt) {
        const int k0 = kt * 32;
        #pragma unroll
        for (int s = 0; s < 2; ++s) {
            const float* xa = &x[(size_t)(m0 + srow + s * 64) * 1024 + k0 + skof];
            const float* wb = &W_ih[(size_t)(n0 + srow + s * 64) * 1024 + k0 + skof];
            ldA[s][0] = *(const f4*)xa; ldA[s][1] = *(const f4*)(xa + 4);
            ldB[s][0] = *(const f4*)wb; ldB[s][1] = *(const f4*)(wb + 4);
        }
    };
    auto XG_WRITE = [&](int buf) {
        #pragma unroll
        for (int s = 0; s < 2; ++s) {
            h8 va, vb;
            #pragma unroll
            for (int c = 0; c < 8; ++c) {
                va[c] = (_Float16)ldA[s][c >> 2][c & 3];
                vb[c] = (_Float16)ldB[s][c >> 2][c & 3];
            }
            *(h8*)&As[buf][srow + s * 64][skof] = va;
            *(h8*)&Bs[buf][srow + s * 64][skof] = vb;
        }
    };

    XG_LOAD(0);
    XG_WRITE(0);
    __syncthreads();
    for (int kt = 0; kt < 32; ++kt) {
        const int cur = kt & 1;
        if (kt + 1 < 32) XG_LOAD(kt + 1);
        h8 af[4], bf[4];
        #pragma unroll
        for (int mf = 0; mf < 4; ++mf) af[mf] = *(const h8*)&As[cur][wr + mf * 16 + lr][lg * 8];
        #pragma unroll
        for (int nf = 0; nf < 4; ++nf) bf[nf] = *(const h8*)&Bs[cur][wc + nf * 16 + lr][lg * 8];
        #pragma unroll
        for (int mf = 0; mf < 4; ++mf)
            #pragma unroll
            for (int nf = 0; nf < 4; ++nf)
                acc[mf][nf] = __builtin_amdgcn_mfma_f32_16x16x32_f16(af[mf], bf[nf], acc[mf][nf], 0, 0, 0);
        if (kt + 1 < 32) XG_WRITE((kt + 1) & 1);
        __syncthreads();
    }
    #pragma unroll
    for (int nf = 0; nf < 4; ++nf) {
        const int col  = n0 + wc + nf * 16 + lr;
        const float bv = bias[col];
        const int gate = col >> 8;
        const int w8   = (col >> 5) & 7;
        const int jt   = (col >> 4) & 1;
        #pragma unroll
        for (int mf = 0; mf < 4; ++mf) {
            const int rowb = m0 + wr + mf * 16 + lg * 4;
            const int tt = rowb >> 8;
            const int gb = (rowb >> 4) & 15;
            h4 pk;
            #pragma unroll
            for (int r = 0; r < 4; ++r) pk[r] = (_Float16)(acc[mf][nf][r] + bv);
            *(h4*)&xg2[((((size_t)tt * 16 + gb) * 8 + w8) * 64 + l) * 32 + gate * 8 + jt * 4] = pk;
        }
    }
}

// ---------------------------------------------------------------- recurrence
// R9 EXACT (best measured: 1508 us). 16 blocks x 512 thr (8 waves, 2/SIMD).
// Wave w owns j in [w*32,(w+1)*32): 8 tiles ti = gate*2 + jt, 8 kb each.
//   VGPR 24 : kb 0,1,2 all ti
//   LDS  17 : kb 3 -> ti, kb 4 -> 8+ti, kb 5/ti==0 -> 16
//   STREAM 23: kb5 ti 1..7, kb6 all, kb7 all (re-read from L2 each step)
__global__ __launch_bounds__(512, 2) void k_lstm_8w(
    const _Float16* __restrict__ xg2, const _Float16* __restrict__ Wp,
    _Float16* __restrict__ h_all)
{
    __shared__ _Float16 wlds[8 * 17 * 512];   // 139,264 B
    __shared__ _Float16 h_sh[2][16][264];     //  16,896 B  (total 156,160)
    const int tid = threadIdx.x;
    const int w  = tid >> 6;       // 0..7
    const int l  = tid & 63;
    const int lr = l & 15;
    const int lg = l >> 4;
    const int g  = blockIdx.x;
    const int b0 = g * 16;

    auto fgid = [&](int ti, int kb) {   // ti = gate*2+jt -> gt = gate*16 + w*2 + jt
        return (((ti >> 1) * 16 + w * 2 + (ti & 1)) * 8 + kb);
    };
    auto ldfrag = [&](int ti, int kb) {
        return *(const h8*)&Wp[((size_t)fgid(ti, kb) * 64 + l) * 8];
    };

    // ---- 24 VGPR-resident frags (kb 0..2)
    h8 wvg[24];
    #pragma unroll
    for (int kb = 0; kb < 3; ++kb)
        #pragma unroll
        for (int ti = 0; ti < 8; ++ti)
            wvg[kb * 8 + ti] = ldfrag(ti, kb);

    // ---- 17 LDS frags per wave
    #pragma unroll
    for (int ti = 0; ti < 8; ++ti)
        *(h8*)&wlds[((w * 17 + ti) * 64 + l) * 8] = ldfrag(ti, 3);
    #pragma unroll
    for (int ti = 0; ti < 8; ++ti)
        *(h8*)&wlds[((w * 17 + 8 + ti) * 64 + l) * 8] = ldfrag(ti, 4);
    *(h8*)&wlds[((w * 17 + 16) * 64 + l) * 8] = ldfrag(0, 5);

    // zero h_sh
    {
        _Float16* p = &h_sh[0][0][0];
        for (int i = tid; i < 2 * 16 * 264; i += 512) p[i] = (_Float16)0.f;
    }
    __syncthreads();

    float c[8];
    #pragma unroll
    for (int i = 0; i < 8; ++i) c[i] = 0.f;

    for (int t = 0; t < 256; ++t) {
        const int cur = t & 1;
        const int nxt = cur ^ 1;

        // xg packet: 64 B/lane, fully coalesced (4 x h8)
        const size_t E = ((((size_t)t * 16 + g) * 8 + w) * 64 + l) * 32;
        h8 xq[4];
        #pragma unroll
        for (int q = 0; q < 4; ++q) xq[q] = *(const h8*)&xg2[E + q * 8];

        // 23 streamed frags, issued at step start (first use at kb5 -> slack);
        // soff anti-hoist keeps them re-read from L2 instead of hoisted.
        unsigned soff = 0;
        asm volatile("" : "+v"(soff));
        h8 sv[23];
        #pragma unroll
        for (int ti = 1; ti < 8; ++ti)
            sv[ti - 1] = *(const h8*)&Wp[((size_t)fgid(ti, 5) * 64 + l) * 8 + soff];
        #pragma unroll
        for (int ti = 0; ti < 8; ++ti)
            sv[7 + ti] = *(const h8*)&Wp[((size_t)fgid(ti, 6) * 64 + l) * 8 + soff];
        #pragma unroll
        for (int ti = 0; ti < 8; ++ti)
            sv[15 + ti] = *(const h8*)&Wp[((size_t)fgid(ti, 7) * 64 + l) * 8 + soff];

        // acc init = xg (MFMA C-operand accumulates the matmul on top)
        f32x4 acc[8];
        #pragma unroll
        for (int ti = 0; ti < 8; ++ti) {
            #pragma unroll
            for (int r = 0; r < 4; ++r)
                acc[ti][r] = (float)xq[ti >> 1][(ti & 1) * 4 + r];
        }

        #pragma unroll
        for (int kb = 0; kb < 8; ++kb) {
            const h8 av = *(const h8*)&h_sh[cur][lr][kb * 32 + lg * 8];
            #pragma unroll
            for (int ti = 0; ti < 8; ++ti) {
                h8 b;
                if (kb < 3)                  b = wvg[kb * 8 + ti];
                else if (kb == 3)            b = *(const h8*)&wlds[((w * 17 + ti) * 64 + l) * 8];
                else if (kb == 4)            b = *(const h8*)&wlds[((w * 17 + 8 + ti) * 64 + l) * 8];
                else if (kb == 5 && ti == 0) b = *(const h8*)&wlds[((w * 17 + 16) * 64 + l) * 8];
                else if (kb == 5)            b = sv[ti - 1];
                else if (kb == 6)            b = sv[7 + ti];
                else                         b = sv[15 + ti];
                acc[ti] = __builtin_amdgcn_mfma_f32_16x16x32_f16(av, b, acc[ti], 0, 0, 0);
            }
        }

        // activations: lane holds z for b = lg*4+r, j = w*32+jt*16+lr, all gates
        #pragma unroll
        for (int jt = 0; jt < 2; ++jt) {
            #pragma unroll
            for (int r = 0; r < 4; ++r) {
                const float ig = fast_sigmoid(acc[0 * 2 + jt][r]);
                const float fg = fast_sigmoid(acc[1 * 2 + jt][r]);
                const float gg = fast_tanh(acc[2 * 2 + jt][r]);
                const float og = fast_sigmoid(acc[3 * 2 + jt][r]);
                const int ci = jt * 4 + r;
                c[ci] = fg * c[ci] + ig * gg;
                const float hv = og * fast_tanh(c[ci]);
                const _Float16 h16 = (_Float16)hv;
                h_sh[nxt][lg * 4 + r][w * 32 + jt * 16 + lr] = h16;
                h_all[((size_t)t * 256 + b0 + lg * 4 + r) * 256 + w * 32 + jt * 16 + lr] = h16;
            }
        }
        __syncthreads();
    }
}

// ---------------------------------------------------------------- FC1+FC2
template <typename HT>
__global__ __launch_bounds__(256) void k_fc(
    const HT* __restrict__ h_all, const float* __restrict__ W1,
    const float* __restrict__ b1, const float* __restrict__ W2,
    const float* __restrict__ b2, float* __restrict__ out)
{
    __shared__ __align__(16) float smem[12288];
    float* hsT = smem;
    float* w1T = smem + 4096;
    const int tid = threadIdx.x;
    const int m0 = blockIdx.x * 64;
    const int tx = tid & 15;
    const int ty = tid >> 4;
    const int r0 = ty * 4;
    const int fA = tx * 4;
    const int fB = 64 + tx * 4;
    float acc[4][8] = {};
    for (int kc = 0; kc < 4; ++kc) {
        const int k0 = kc * 64;
        __syncthreads();
        #pragma unroll
        for (int i = 0; i < 4; ++i) {
            const int fid = tid + i * 256;
            const int rr = fid >> 4;
            const int qq = fid & 15;
            const HT* p = &h_all[(size_t)(m0 + rr) * 256 + k0 + qq * 4];
            f4 v;
            if constexpr (std::is_same<HT, float>::value) {
                v = *(const f4*)p;
            } else {
                v[0] = ldf(p); v[1] = ldf(p + 1); v[2] = ldf(p + 2); v[3] = ldf(p + 3);
            }
            #pragma unroll
            for (int cc = 0; cc < 4; ++cc)
                hsT[(qq * 4 + cc) * 64 + rr] = fmaxf(v[cc], 0.f);
        }
        #pragma unroll
        for (int i = 0; i < 8; ++i) {
            const int fid = tid + i * 256;
            const int ff = fid >> 4;
            const int qq = fid & 15;
            const f4 v = *(const f4*)&W1[(size_t)ff * 256 + k0 + qq * 4];
            #pragma unroll
            for (int cc = 0; cc < 4; ++cc)
                w1T[(qq * 4 + cc) * 128 + ff] = v[cc];
        }
        __syncthreads();
        #pragma unroll 4
        for (int kk = 0; kk < 64; ++kk) {
            const f4 aa = *(const f4*)&hsT[kk * 64 + r0];
            const f4 ba = *(const f4*)&w1T[kk * 128 + fA];
            const f4 bb = *(const f4*)&w1T[kk * 128 + fB];
            #pragma unroll
            for (int i = 0; i < 4; ++i) {
                #pragma unroll
                for (int j = 0; j < 4; ++j) {
                    acc[i][j]     = fmaf(aa[i], ba[j], acc[i][j]);
                    acc[i][j + 4] = fmaf(aa[i], bb[j], acc[i][j + 4]);
                }
            }
        }
    }
    __syncthreads();
    float* fc1s = smem;
    #pragma unroll
    for (int j = 0; j < 4; ++j) {
        const float bbA = b1[fA + j];
        const float bbB = b1[fB + j];
        #pragma unroll
        for (int i = 0; i < 4; ++i) {
            fc1s[(r0 + i) * 132 + fA + j] = fmaxf(acc[i][j] + bbA, 0.f);
            fc1s[(r0 + i) * 132 + fB + j] = fmaxf(acc[i][j + 4] + bbB, 0.f);
        }
    }
    __syncthreads();
    const int r  = tid >> 2;
    const int c0 = (tid & 3) * 2;
    float o0 = b2[c0], o1 = b2[c0 + 1];
    #pragma unroll
    for (int fq = 0; fq < 32; ++fq) {
        const f4 p  = *(const f4*)&fc1s[r * 132 + fq * 4];
        const f4 wa = *(const f4*)&W2[(size_t)c0 * 128 + fq * 4];
        const f4 wb = *(const f4*)&W2[(size_t)(c0 + 1) * 128 + fq * 4];
        o0 += p[0] * wa[0] + p[1] * wa[1] + p[2] * wa[2] + p[3] * wa[3];
        o1 += p[0] * wb[0] + p[1] * wb[1] + p[2] * wb[2] + p[3] * wb[3];
    }
    out[(size_t)(m0 + r) * 8 + c0]     = o0;
    out[(size_t)(m0 + r) * 8 + c0 + 1] = o1;
}

// ---------------------------------------------------------------- launch
extern "C" void kernel_launch(void* const* d_in, const int* in_sizes, int n_in,
                              void* d_out, int out_size, void* d_ws, size_t ws_size,
                              hipStream_t stream)
{
    const float* x    = (const float*)d_in[0];
    const float* W_ih = (const float*)d_in[1];
    const float* W_hh = (const float*)d_in[2];
    const float* b_ih = (const float*)d_in[3];
    const float* b_hh = (const float*)d_in[4];
    const float* W1   = (const float*)d_in[5];
    const float* b1   = (const float*)d_in[6];
    const float* W2   = (const float*)d_in[7];
    const float* b2   = (const float*)d_in[8];
    float* out = (float*)d_out;
    char* ws = (char*)d_ws;

    // workspace layout (168,300,544 B)
    _Float16* xg2   = (_Float16*)ws;                          // 134,217,728 B
    _Float16* h_all = (_Float16*)(ws + 134217728);            //  33,554,432 B
    _Float16* Wp    = (_Float16*)(ws + 167772160);            //     524,288 B
    float*    bias  = (float*)   (ws + 168296448);            //       4,096 B

    k_bias<<<4, 256, 0, stream>>>(b_ih, b_hh, bias);
    k_pack<<<128, 256, 0, stream>>>(W_hh, Wp);
    k_xg_mfma<<<dim3(8, 512), 256, 0, stream>>>(x, W_ih, bias, xg2);
    k_lstm_8w<<<16, 512, 0, stream>>>(xg2, Wp, h_all);
    k_fc<_Float16><<<1024, 256, 0, stream>>>(h_all, W1, b1, W2, b2, out);
}

// Round 17
// 1821.640 us; speedup vs baseline: 6.1232x; 1.0414x over previous
//
#include <hip/hip_runtime.h>
#include <type_traits>

// LSTM_69879117906487: T=256,B=256,I=1024,H=256,FC=128,C=8
// Round 17: R16 (1897us, passing) + MFMA-ized k_fc.
//   Old k_fc: fp32 VALU GEMM w/ SCALAR half->float LDS staging (~160us).
//   New: FC1 = fp16 MFMA ([65536x256]x[256x128], fp32 accum, relu on A-frags
//   via packed fp16 max), FC2 (C=8) = fp32 VALU from LDS. W1 packed into MFMA
//   B-layout by k_pack1 into the Wp region (free after k_lstm -- same stream).
// Recurrence = R9 exact (7-structure plateau floor, 1502us).
// k_xg = XCD-swizzled (R16).

typedef float    f4    __attribute__((ext_vector_type(4)));
typedef float    f32x4 __attribute__((ext_vector_type(4)));
typedef _Float16 h8    __attribute__((ext_vector_type(8)));
typedef _Float16 h4    __attribute__((ext_vector_type(4)));

__device__ __forceinline__ float fast_sigmoid(float x) {
    return 1.f / (1.f + __expf(-x));
}
__device__ __forceinline__ float fast_tanh(float x) {
    const float e = __expf(-2.f * fabsf(x));
    const float t = (1.f - e) / (1.f + e);
    return copysignf(t, x);
}

// ---------------------------------------------------------------- bias
__global__ __launch_bounds__(256) void k_bias(const float* __restrict__ b_ih,
                                              const float* __restrict__ b_hh,
                                              float* __restrict__ bias) {
    const int i = blockIdx.x * 256 + threadIdx.x;
    if (i < 1024) bias[i] = b_ih[i] + b_hh[i];
}

// ---------------------------------------------------------------- W_hh pack
// fi = gt*8 + kb (gt = 16-gate tile 0..63, kb = 32-k block 0..7).
// Lane l elem j: W_hh[gt*16 + (l&15)][kb*32 + (l>>4)*8 + j]; 16 B/lane.
__global__ __launch_bounds__(256) void k_pack(const float* __restrict__ W_hh,
                                              _Float16* __restrict__ Wp) {
    const int idx = blockIdx.x * 256 + threadIdx.x;
    const int fi = idx >> 6;
    const int l  = idx & 63;
    const int g  = (fi >> 3) * 16 + (l & 15);
    const int k  = (fi & 7) * 32 + ((l >> 4) << 3);
    const float* src = &W_hh[(size_t)g * 256 + k];
    h8 v;
    #pragma unroll
    for (int c = 0; c < 8; ++c) v[c] = (_Float16)src[c];
    *(h8*)&Wp[(size_t)idx * 8] = v;
}

// ---------------------------------------------------------------- W1 pack (for k_fc)
// 64 frags: fi = nt*8 + kb (nt = 16-col tile 0..7, kb = 32-k block 0..7).
// Lane l elem j: W1[nt*16 + (l&15)][kb*32 + (l>>4)*8 + j].
__global__ __launch_bounds__(256) void k_pack1(const float* __restrict__ W1,
                                               _Float16* __restrict__ Wp1) {
    const int idx = blockIdx.x * 256 + threadIdx.x;   // 4096 total
    const int fi = idx >> 6;
    const int l  = idx & 63;
    const int row = (fi >> 3) * 16 + (l & 15);
    const int k   = (fi & 7) * 32 + ((l >> 4) << 3);
    const float* src = &W1[(size_t)row * 256 + k];
    h8 v;
    #pragma unroll
    for (int c = 0; c < 8; ++c) v[c] = (_Float16)src[c];
    *(h8*)&Wp1[(size_t)idx * 8] = v;
}

// ---------------------------------------------------------------- xg GEMM (MFMA)
// 128x128 tile, BK=32, 256 thr. XCD-swizzled block mapping (R16).
// Epilogue -> xg2 packets: base = (((t*16+g)*8 + w8)*64 + lane)*32,
// elem = gate*8 + jt*4 + r.
__global__ __launch_bounds__(256) void k_xg_mfma(
    const float* __restrict__ x, const float* __restrict__ W_ih,
    const float* __restrict__ bias, _Float16* __restrict__ xg2)
{
    __shared__ _Float16 As[2][128][40];
    __shared__ _Float16 Bs[2][128][40];
    const int tid = threadIdx.x;
    const int l   = tid & 63;
    const int w   = tid >> 6;
    const int bid = blockIdx.y * 8 + blockIdx.x;
    const int swz = (bid & 7) * 512 + (bid >> 3);
    const int m0  = (swz >> 3) * 128;
    const int n0  = (swz & 7) * 128;
    const int wr  = (w >> 1) * 64;
    const int wc  = (w & 1) * 64;
    const int srow = tid >> 2;
    const int skof = (tid & 3) * 8;
    const int lr = l & 15;
    const int lg = l >> 4;

    f32x4 acc[4][4] = {};
    f4 ldA[2][2], ldB[2][2];

    auto XG_LOAD = [&](int kt) {
        const int k0 = kt * 32;
        #pragma unroll
        for (int s = 0; s < 2; ++s) {
            const float* xa = &x[(size_t)(m0 + srow + s * 64) * 1024 + k0 + skof];
            const float* wb = &W_ih[(size_t)(n0 + srow + s * 64) * 1024 + k0 + skof];
            ldA[s][0] = *(const f4*)xa; ldA[s][1] = *(const f4*)(xa + 4);
            ldB[s][0] = *(const f4*)wb; ldB[s][1] = *(const f4*)(wb + 4);
        }
    };
    auto XG_WRITE = [&](int buf) {
        #pragma unroll
        for (int s = 0; s < 2; ++s) {
            h8 va, vb;
            #pragma unroll
            for (int c = 0; c < 8; ++c) {
                va[c] = (_Float16)ldA[s][c >> 2][c & 3];
                vb[c] = (_Float16)ldB[s][c >> 2][c & 3];
            }
            *(h8*)&As[buf][srow + s * 64][skof] = va;
            *(h8*)&Bs[buf][srow + s * 64][skof] = vb;
        }
    };

    XG_LOAD(0);
    XG_WRITE(0);
    __syncthreads();
    for (int kt = 0; kt < 32; ++kt) {
        const int cur = kt & 1;
        if (kt + 1 < 32) XG_LOAD(kt + 1);
        h8 af[4], bf[4];
        #pragma unroll
        for (int mf = 0; mf < 4; ++mf) af[mf] = *(const h8*)&As[cur][wr + mf * 16 + lr][lg * 8];
        #pragma unroll
        for (int nf = 0; nf < 4; ++nf) bf[nf] = *(const h8*)&Bs[cur][wc + nf * 16 + lr][lg * 8];
        #pragma unroll
        for (int mf = 0; mf < 4; ++mf)
            #pragma unroll
            for (int nf = 0; nf < 4; ++nf)
                acc[mf][nf] = __builtin_amdgcn_mfma_f32_16x16x32_f16(af[mf], bf[nf], acc[mf][nf], 0, 0, 0);
        if (kt + 1 < 32) XG_WRITE((kt + 1) & 1);
        __syncthreads();
    }
    #pragma unroll
    for (int nf = 0; nf < 4; ++nf) {
        const int col  = n0 + wc + nf * 16 + lr;
        const float bv = bias[col];
        const int gate = col >> 8;
        const int w8   = (col >> 5) & 7;
        const int jt   = (col >> 4) & 1;
        #pragma unroll
        for (int mf = 0; mf < 4; ++mf) {
            const int rowb = m0 + wr + mf * 16 + lg * 4;
            const int tt = rowb >> 8;
            const int gb = (rowb >> 4) & 15;
            h4 pk;
            #pragma unroll
            for (int r = 0; r < 4; ++r) pk[r] = (_Float16)(acc[mf][nf][r] + bv);
            *(h4*)&xg2[((((size_t)tt * 16 + gb) * 8 + w8) * 64 + l) * 32 + gate * 8 + jt * 4] = pk;
        }
    }
}

// ---------------------------------------------------------------- recurrence (R9 exact)
__global__ __launch_bounds__(512, 2) void k_lstm_8w(
    const _Float16* __restrict__ xg2, const _Float16* __restrict__ Wp,
    _Float16* __restrict__ h_all)
{
    __shared__ _Float16 wlds[8 * 17 * 512];   // 139,264 B
    __shared__ _Float16 h_sh[2][16][264];     //  16,896 B  (total 156,160)
    const int tid = threadIdx.x;
    const int w  = tid >> 6;
    const int l  = tid & 63;
    const int lr = l & 15;
    const int lg = l >> 4;
    const int g  = blockIdx.x;
    const int b0 = g * 16;

    auto fgid = [&](int ti, int kb) {
        return (((ti >> 1) * 16 + w * 2 + (ti & 1)) * 8 + kb);
    };
    auto ldfrag = [&](int ti, int kb) {
        return *(const h8*)&Wp[((size_t)fgid(ti, kb) * 64 + l) * 8];
    };

    h8 wvg[24];
    #pragma unroll
    for (int kb = 0; kb < 3; ++kb)
        #pragma unroll
        for (int ti = 0; ti < 8; ++ti)
            wvg[kb * 8 + ti] = ldfrag(ti, kb);

    #pragma unroll
    for (int ti = 0; ti < 8; ++ti)
        *(h8*)&wlds[((w * 17 + ti) * 64 + l) * 8] = ldfrag(ti, 3);
    #pragma unroll
    for (int ti = 0; ti < 8; ++ti)
        *(h8*)&wlds[((w * 17 + 8 + ti) * 64 + l) * 8] = ldfrag(ti, 4);
    *(h8*)&wlds[((w * 17 + 16) * 64 + l) * 8] = ldfrag(0, 5);

    {
        _Float16* p = &h_sh[0][0][0];
        for (int i = tid; i < 2 * 16 * 264; i += 512) p[i] = (_Float16)0.f;
    }
    __syncthreads();

    float c[8];
    #pragma unroll
    for (int i = 0; i < 8; ++i) c[i] = 0.f;

    for (int t = 0; t < 256; ++t) {
        const int cur = t & 1;
        const int nxt = cur ^ 1;

        const size_t E = ((((size_t)t * 16 + g) * 8 + w) * 64 + l) * 32;
        h8 xq[4];
        #pragma unroll
        for (int q = 0; q < 4; ++q) xq[q] = *(const h8*)&xg2[E + q * 8];

        unsigned soff = 0;
        asm volatile("" : "+v"(soff));
        h8 sv[23];
        #pragma unroll
        for (int ti = 1; ti < 8; ++ti)
            sv[ti - 1] = *(const h8*)&Wp[((size_t)fgid(ti, 5) * 64 + l) * 8 + soff];
        #pragma unroll
        for (int ti = 0; ti < 8; ++ti)
            sv[7 + ti] = *(const h8*)&Wp[((size_t)fgid(ti, 6) * 64 + l) * 8 + soff];
        #pragma unroll
        for (int ti = 0; ti < 8; ++ti)
            sv[15 + ti] = *(const h8*)&Wp[((size_t)fgid(ti, 7) * 64 + l) * 8 + soff];

        f32x4 acc[8];
        #pragma unroll
        for (int ti = 0; ti < 8; ++ti) {
            #pragma unroll
            for (int r = 0; r < 4; ++r)
                acc[ti][r] = (float)xq[ti >> 1][(ti & 1) * 4 + r];
        }

        #pragma unroll
        for (int kb = 0; kb < 8; ++kb) {
            const h8 av = *(const h8*)&h_sh[cur][lr][kb * 32 + lg * 8];
            #pragma unroll
            for (int ti = 0; ti < 8; ++ti) {
                h8 b;
                if (kb < 3)                  b = wvg[kb * 8 + ti];
                else if (kb == 3)            b = *(const h8*)&wlds[((w * 17 + ti) * 64 + l) * 8];
                else if (kb == 4)            b = *(const h8*)&wlds[((w * 17 + 8 + ti) * 64 + l) * 8];
                else if (kb == 5 && ti == 0) b = *(const h8*)&wlds[((w * 17 + 16) * 64 + l) * 8];
                else if (kb == 5)            b = sv[ti - 1];
                else if (kb == 6)            b = sv[7 + ti];
                else                         b = sv[15 + ti];
                acc[ti] = __builtin_amdgcn_mfma_f32_16x16x32_f16(av, b, acc[ti], 0, 0, 0);
            }
        }

        #pragma unroll
        for (int jt = 0; jt < 2; ++jt) {
            #pragma unroll
            for (int r = 0; r < 4; ++r) {
                const float ig = fast_sigmoid(acc[0 * 2 + jt][r]);
                const float fg = fast_sigmoid(acc[1 * 2 + jt][r]);
                const float gg = fast_tanh(acc[2 * 2 + jt][r]);
                const float og = fast_sigmoid(acc[3 * 2 + jt][r]);
                const int ci = jt * 4 + r;
                c[ci] = fg * c[ci] + ig * gg;
                const float hv = og * fast_tanh(c[ci]);
                const _Float16 h16 = (_Float16)hv;
                h_sh[nxt][lg * 4 + r][w * 32 + jt * 16 + lr] = h16;
                h_all[((size_t)t * 256 + b0 + lg * 4 + r) * 256 + w * 32 + jt * 16 + lr] = h16;
            }
        }
        __syncthreads();
    }
}

// ---------------------------------------------------------------- FC1 (MFMA) + FC2
// 512 blocks x 256 thr (4 waves). Block: 128 rows. Wave w: rows [32w,32w+32).
// FC1: A = relu(h) fp16 direct-from-global h8 loads (packed fp16 max), B = Wp1
// frags from LDS, fp32 accum. FC2: fp32 VALU from fc1s LDS.
__global__ __launch_bounds__(256) void k_fc_mfma(
    const _Float16* __restrict__ h_all, const _Float16* __restrict__ Wp1,
    const float* __restrict__ b1, const float* __restrict__ W2,
    const float* __restrict__ b2, float* __restrict__ out)
{
    __shared__ _Float16 w1f[64 * 512];    // 65,536 B: 64 B-frags
    __shared__ float    fc1s[128 * 132];  // 67,584 B (pad 132)
    const int tid = threadIdx.x;
    const int w  = tid >> 6;
    const int l  = tid & 63;
    const int lr = l & 15;
    const int lg = l >> 4;
    const int m0 = blockIdx.x * 128;

    // stage Wp1 into LDS (straight copy, 16 h8/thread)
    #pragma unroll
    for (int i = 0; i < 16; ++i) {
        const int idx = tid + i * 256;
        *(h8*)&w1f[idx * 8] = *(const h8*)&Wp1[(size_t)idx * 8];
    }
    __syncthreads();

    // FC1: per wave 2 m-frags x 8 n-frags, K = 8 kb
    f32x4 acc[2][8] = {};
    #pragma unroll
    for (int kb = 0; kb < 8; ++kb) {
        h8 a[2];
        #pragma unroll
        for (int mt = 0; mt < 2; ++mt) {
            h8 v = *(const h8*)&h_all[(size_t)(m0 + w * 32 + mt * 16 + lr) * 256 + kb * 32 + lg * 8];
            #pragma unroll
            for (int cc = 0; cc < 8; ++cc)
                v[cc] = v[cc] > (_Float16)0.f ? v[cc] : (_Float16)0.f;   // relu (pk_max)
            a[mt] = v;
        }
        #pragma unroll
        for (int nt = 0; nt < 8; ++nt) {
            const h8 b = *(const h8*)&w1f[((nt * 8 + kb) * 64 + l) * 8];
            acc[0][nt] = __builtin_amdgcn_mfma_f32_16x16x32_f16(a[0], b, acc[0][nt], 0, 0, 0);
            acc[1][nt] = __builtin_amdgcn_mfma_f32_16x16x32_f16(a[1], b, acc[1][nt], 0, 0, 0);
        }
    }
    // epilogue: relu(acc + b1) -> fc1s. C layout: col = nt*16+lr, row = lg*4+r.
    #pragma unroll
    for (int nt = 0; nt < 8; ++nt) {
        const int col = nt * 16 + lr;
        const float bv = b1[col];
        #pragma unroll
        for (int mt = 0; mt < 2; ++mt) {
            const int row = w * 32 + mt * 16 + lg * 4;
            #pragma unroll
            for (int r = 0; r < 4; ++r)
                fc1s[(row + r) * 132 + col] = fmaxf(acc[mt][nt][r] + bv, 0.f);
        }
    }
    __syncthreads();

    // FC2: 1024 outputs / 256 thr = 4 each. r = tid>>1, cols cpair..cpair+3.
    const int r  = tid >> 1;            // 0..127
    const int c0 = (tid & 1) * 4;       // 0 or 4
    float o[4] = {b2[c0], b2[c0 + 1], b2[c0 + 2], b2[c0 + 3]};
    #pragma unroll 8
    for (int fq = 0; fq < 32; ++fq) {
        const f4 p = *(const f4*)&fc1s[r * 132 + fq * 4];
        #pragma unroll
        for (int cc = 0; cc < 4; ++cc) {
            const f4 wv = *(const f4*)&W2[(size_t)(c0 + cc) * 128 + fq * 4];
            o[cc] += p[0] * wv[0] + p[1] * wv[1] + p[2] * wv[2] + p[3] * wv[3];
        }
    }
    *(f4*)&out[(size_t)(m0 + r) * 8 + c0] = *(f4*)o;
}

// ---------------------------------------------------------------- launch
extern "C" void kernel_launch(void* const* d_in, const int* in_sizes, int n_in,
                              void* d_out, int out_size, void* d_ws, size_t ws_size,
                              hipStream_t stream)
{
    const float* x    = (const float*)d_in[0];
    const float* W_ih = (const float*)d_in[1];
    const float* W_hh = (const float*)d_in[2];
    const float* b_ih = (const float*)d_in[3];
    const float* b_hh = (const float*)d_in[4];
    const float* W1   = (const float*)d_in[5];
    const float* b1   = (const float*)d_in[6];
    const float* W2   = (const float*)d_in[7];
    const float* b2   = (const float*)d_in[8];
    float* out = (float*)d_out;
    char* ws = (char*)d_ws;

    // workspace layout (168,300,544 B -- unchanged, proven)
    _Float16* xg2   = (_Float16*)ws;                          // 134,217,728 B
    _Float16* h_all = (_Float16*)(ws + 134217728);            //  33,554,432 B
    _Float16* Wp    = (_Float16*)(ws + 167772160);            //     524,288 B
    float*    bias  = (float*)   (ws + 168296448);            //       4,096 B
    _Float16* Wp1   = Wp;   // Wp region reused AFTER k_lstm (stream-ordered)

    k_bias<<<4, 256, 0, stream>>>(b_ih, b_hh, bias);
    k_pack<<<128, 256, 0, stream>>>(W_hh, Wp);
    k_xg_mfma<<<dim3(8, 512), 256, 0, stream>>>(x, W_ih, bias, xg2);
    k_lstm_8w<<<16, 512, 0, stream>>>(xg2, Wp, h_all);
    k_pack1<<<16, 256, 0, stream>>>(W1, Wp1);                 // overwrites Wp
    k_fc_mfma<<<512, 256, 0, stream>>>(h_all, Wp1, b1, W2, b2, out);
}